// Round 1
// baseline (1276.693 us; speedup 1.0000x reference)
//
#include <hip/hip_runtime.h>
#include <hip/hip_bf16.h>
#include <cstddef>

#define NXX 512
#define NUU 128
#define NDD 64
#define BB  256
#define TT  256
#define CL  8
#define NC  32
#define BS  (BB * NXX)
#define MS  (NXX * NXX)
#define LDK 40

typedef __attribute__((ext_vector_type(8))) short short8;
typedef __attribute__((ext_vector_type(4))) float f32x4;
typedef __attribute__((ext_vector_type(4))) unsigned short ushort4v;

__device__ __forceinline__ unsigned short f2bf(float f) {
    union { float f; unsigned u; } v; v.f = f;
    unsigned r = v.u + 0x7FFFu + ((v.u >> 16) & 1u);
    return (unsigned short)(r >> 16);
}

template<bool BT_NATURAL>
__device__ __forceinline__ void gemm_mainloop(
    f32x4 (&acc)[4][4],
    const float* __restrict__ A, int lda,
    const float* __restrict__ B, int ldb,
    int K, int row0, int n0,
    unsigned short (*As)[LDK], unsigned short (*Bs)[LDK])
{
    const int tid  = threadIdx.x;
    const int lane = tid & 63;
    const int wave = tid >> 6;
    const int wm   = (wave >> 1) * 64;
    const int wn   = (wave & 1) * 64;
    const int l16  = lane & 15;
    const int quad = lane >> 4;

    for (int k0 = 0; k0 < K; k0 += 32) {
        __syncthreads();
#pragma unroll
        for (int i = 0; i < 4; ++i) {
            int idx = tid + i * 256;
            int r   = idx >> 3;
            int c   = (idx & 7) << 2;
            float4 v = *(const float4*)(A + (size_t)(row0 + r) * lda + k0 + c);
            ushort4v h = { f2bf(v.x), f2bf(v.y), f2bf(v.z), f2bf(v.w) };
            *(ushort4v*)&As[r][c] = h;
        }
        if (BT_NATURAL) {
#pragma unroll
            for (int i = 0; i < 4; ++i) {
                int idx = tid + i * 256;
                int r   = idx >> 3;
                int c   = (idx & 7) << 2;
                float4 v = *(const float4*)(B + (size_t)(n0 + r) * ldb + k0 + c);
                ushort4v h = { f2bf(v.x), f2bf(v.y), f2bf(v.z), f2bf(v.w) };
                *(ushort4v*)&Bs[r][c] = h;
            }
        } else {
#pragma unroll
            for (int i = 0; i < 4; ++i) {
                int idx = tid + i * 256;
                int k   = idx >> 5;
                int n   = (idx & 31) << 2;
                float4 v = *(const float4*)(B + (size_t)(k0 + k) * ldb + n0 + n);
                Bs[n + 0][k] = f2bf(v.x);
                Bs[n + 1][k] = f2bf(v.y);
                Bs[n + 2][k] = f2bf(v.z);
                Bs[n + 3][k] = f2bf(v.w);
            }
        }
        __syncthreads();
        short8 af[4], bfr[4];
#pragma unroll
        for (int f = 0; f < 4; ++f)
            af[f] = *(const short8*)&As[wm + f * 16 + l16][quad * 8];
#pragma unroll
        for (int f = 0; f < 4; ++f)
            bfr[f] = *(const short8*)&Bs[wn + f * 16 + l16][quad * 8];
#pragma unroll
        for (int fm = 0; fm < 4; ++fm)
#pragma unroll
            for (int fn = 0; fn < 4; ++fn)
                acc[fm][fn] = __builtin_amdgcn_mfma_f32_16x16x32_bf16(
                    af[fm], bfr[fn], acc[fm][fn], 0, 0, 0);
    }
}

__device__ __forceinline__ void gemm_epilogue(
    f32x4 (&acc)[4][4], const float* __restrict__ Cadd,
    float* __restrict__ D, int row0, int n0, float* __restrict__ Yrow)
{
    const int tid  = threadIdx.x;
    const int lane = tid & 63;
    const int wave = tid >> 6;
    const int wm   = (wave >> 1) * 64;
    const int wn   = (wave & 1) * 64;
    const int l16  = lane & 15;
    const int quad = lane >> 4;
#pragma unroll
    for (int fm = 0; fm < 4; ++fm) {
#pragma unroll
        for (int fn = 0; fn < 4; ++fn) {
#pragma unroll
            for (int r = 0; r < 4; ++r) {
                int m = row0 + wm + fm * 16 + quad * 4 + r;
                int n = n0 + wn + fn * 16 + l16;
                size_t off = (size_t)m * NXX + n;
                float val = acc[fm][fn][r];
                if (Cadd) val += Cadd[off];
                D[off] = val;
                if (Yrow && n == NXX - 1) Yrow[m] = val;
            }
        }
    }
}

__global__ __launch_bounds__(256) void k_weff(
    const float* __restrict__ Aw, const float* __restrict__ Asc,
    float* __restrict__ Wout)
{
    const int n   = blockIdx.x;
    const int tid = threadIdx.x;
    const int lane = tid & 63, wave = tid >> 6;
    float v0 = Aw[(size_t)n * NXX + tid];
    float v1 = Aw[(size_t)n * NXX + 256 + tid];
    __shared__ float sred[4];
    float m = fmaxf(v0, v1);
#pragma unroll
    for (int off = 32; off; off >>= 1) m = fmaxf(m, __shfl_down(m, off));
    if (lane == 0) sred[wave] = m;
    __syncthreads();
    if (tid == 0) sred[0] = fmaxf(fmaxf(sred[0], sred[1]), fmaxf(sred[2], sred[3]));
    __syncthreads();
    const float mm = sred[0];
    __syncthreads();
    float e0 = expf(v0 - mm), e1 = expf(v1 - mm);
    float s = e0 + e1;
#pragma unroll
    for (int off = 32; off; off >>= 1) s += __shfl_down(s, off);
    if (lane == 0) sred[wave] = s;
    __syncthreads();
    if (tid == 0) sred[0] = sred[0] + sred[1] + sred[2] + sred[3];
    __syncthreads();
    const float inv = 1.0f / sred[0];
    float sc0 = 1.0f - 0.1f * (1.0f / (1.0f + expf(-Asc[(size_t)n * NXX + tid])));
    float sc1 = 1.0f - 0.1f * (1.0f / (1.0f + expf(-Asc[(size_t)n * NXX + 256 + tid])));
    Wout[(size_t)tid * NXX + n]         = sc0 * e0 * inv;
    Wout[(size_t)(tid + 256) * NXX + n] = sc1 * e1 * inv;
}

struct PowArgs { int a[4]; int b[4]; int d[4]; };

__global__ __launch_bounds__(256) void k_pow(float* __restrict__ powb, PowArgs pa)
{
    const int t = blockIdx.z;
    const float* A = powb + (size_t)pa.a[t] * MS;
    const float* B = powb + (size_t)pa.b[t] * MS;
    float*       D = powb + (size_t)pa.d[t] * MS;
    __shared__ unsigned short As[128][LDK];
    __shared__ unsigned short Bs[128][LDK];
    f32x4 acc[4][4] = {};
    const int row0 = blockIdx.y * 128, n0 = blockIdx.x * 128;
    gemm_mainloop<false>(acc, A, NXX, B, NXX, NXX, row0, n0, As, Bs);
    gemm_epilogue(acc, nullptr, D, row0, n0, nullptr);
}

__global__ __launch_bounds__(256) void k_inj(
    const float* __restrict__ U, const float* __restrict__ Dm,
    const float* __restrict__ Bw, const float* __restrict__ Ew,
    float* __restrict__ Xp)
{
    const int t = blockIdx.z;
    __shared__ unsigned short As[128][LDK];
    __shared__ unsigned short Bs[128][LDK];
    f32x4 acc[4][4] = {};
    const int row0 = blockIdx.y * 128, n0 = blockIdx.x * 128;
    gemm_mainloop<true>(acc, U  + (size_t)t * BB * NUU, NUU, Bw, NUU, NUU, row0, n0, As, Bs);
    gemm_mainloop<true>(acc, Dm + (size_t)t * BB * NDD, NDD, Ew, NDD, NDD, row0, n0, As, Bs);
    gemm_epilogue(acc, nullptr, Xp + (size_t)t * BS, row0, n0, nullptr);
}

__global__ __launch_bounds__(256) void k_scan(
    float* __restrict__ Xp, const float* __restrict__ Weff, int j)
{
    const int c = blockIdx.z;
    const float* Ap = Xp + (size_t)(c * CL + j - 1) * BS;
    float*       Dp = Xp + (size_t)(c * CL + j) * BS;
    __shared__ unsigned short As[128][LDK];
    __shared__ unsigned short Bs[128][LDK];
    f32x4 acc[4][4] = {};
    const int row0 = blockIdx.y * 128, n0 = blockIdx.x * 128;
    gemm_mainloop<false>(acc, Ap, NXX, Weff, NXX, NXX, row0, n0, As, Bs);
    gemm_epilogue(acc, Dp, Dp, row0, n0, nullptr);
}

__global__ __launch_bounds__(256) void k_vinit(
    const float* __restrict__ x, const float* __restrict__ Xp, float* __restrict__ v0)
{
    size_t idx4 = (size_t)blockIdx.x * blockDim.x + threadIdx.x;
    size_t total4 = (size_t)NC * BS / 4;
    if (idx4 >= total4) return;
    size_t e = idx4 * 4;
    int c = (int)(e / BS);
    size_t r = e % BS;
    float4 val;
    if (c == 0) val = *(const float4*)(x + r);
    else        val = *(const float4*)(Xp + (size_t)(c * CL - 1) * BS + r);
    *(float4*)(v0 + e) = val;
}

__global__ __launch_bounds__(256) void k_prefix(
    const float* __restrict__ vsrc, float* __restrict__ vdst,
    const float* __restrict__ Am, int s)
{
    const int c = blockIdx.z + s;
    const float* Ap = vsrc + (size_t)(c - s) * BS;
    const float* Cp = vsrc + (size_t)c * BS;
    float*       Dp = vdst + (size_t)c * BS;
    __shared__ unsigned short As[128][LDK];
    __shared__ unsigned short Bs[128][LDK];
    f32x4 acc[4][4] = {};
    const int row0 = blockIdx.y * 128, n0 = blockIdx.x * 128;
    gemm_mainloop<false>(acc, Ap, NXX, Am, NXX, NXX, row0, n0, As, Bs);
    gemm_epilogue(acc, Cp, Dp, row0, n0, nullptr);
}

__global__ __launch_bounds__(256) void k_corr(
    const float* __restrict__ v, const float* __restrict__ powb,
    float* __restrict__ X, float* __restrict__ Y)
{
    const int z = blockIdx.z;
    const int c = z >> 3, j = z & 7;
    const float* Ap = v + (size_t)c * BS;
    const float* Bp = powb + (size_t)j * MS;
    float*       Dp = X + (size_t)z * BS;
    __shared__ unsigned short As[128][LDK];
    __shared__ unsigned short Bs[128][LDK];
    f32x4 acc[4][4] = {};
    const int row0 = blockIdx.y * 128, n0 = blockIdx.x * 128;
    gemm_mainloop<false>(acc, Ap, NXX, Bp, NXX, NXX, row0, n0, As, Bs);
    gemm_epilogue(acc, Dp, Dp, row0, n0, Y + (size_t)z * BB);
}

extern "C" void kernel_launch(void* const* d_in, const int* in_sizes, int n_in,
                              void* d_out, int out_size, void* d_ws, size_t ws_size,
                              hipStream_t stream)
{
    const float* x   = (const float*)d_in[0];
    const float* U   = (const float*)d_in[1];
    const float* Dm  = (const float*)d_in[2];
    const float* Aw  = (const float*)d_in[3];
    const float* Asc = (const float*)d_in[4];
    const float* Bw  = (const float*)d_in[5];
    const float* Ew  = (const float*)d_in[6];

    float* Xout = (float*)d_out;
    float* Yout = Xout + (size_t)TT * BB * NXX;

    float* powb = (float*)d_ws;              // pow[0..7]=W^1..W^8, pow[8..11]=W^{16,32,64,128}
    float* v0   = powb + (size_t)12 * MS;
    float* v1   = v0 + (size_t)NC * BS;

    dim3 blk(256);

    k_weff<<<dim3(512), blk, 0, stream>>>(Aw, Asc, powb);

    { PowArgs p{{0},{0},{1}};                   k_pow<<<dim3(4,4,1), blk, 0, stream>>>(powb, p); }
    { PowArgs p{{1,1},{0,1},{2,3}};             k_pow<<<dim3(4,4,2), blk, 0, stream>>>(powb, p); }
    { PowArgs p{{3,3,3,3},{0,1,2,3},{4,5,6,7}}; k_pow<<<dim3(4,4,4), blk, 0, stream>>>(powb, p); }
    { PowArgs p{{7},{7},{8}};                   k_pow<<<dim3(4,4,1), blk, 0, stream>>>(powb, p); }
    { PowArgs p{{8},{8},{9}};                   k_pow<<<dim3(4,4,1), blk, 0, stream>>>(powb, p); }
    { PowArgs p{{9},{9},{10}};                  k_pow<<<dim3(4,4,1), blk, 0, stream>>>(powb, p); }
    { PowArgs p{{10},{10},{11}};                k_pow<<<dim3(4,4,1), blk, 0, stream>>>(powb, p); }

    k_inj<<<dim3(4,2,TT), blk, 0, stream>>>(U, Dm, Bw, Ew, Xout);

    for (int j = 1; j < CL; ++j)
        k_scan<<<dim3(4,2,NC), blk, 0, stream>>>(Xout, powb, j);

    k_vinit<<<dim3((NC * BS / 4 + 255) / 256), blk, 0, stream>>>(x, Xout, v0);

    float* src = v0; float* dst = v1;
    for (int k = 0; k < 5; ++k) {
        int s = 1 << k;
        hipMemcpyAsync(dst, src, (size_t)s * BS * sizeof(float),
                       hipMemcpyDeviceToDevice, stream);
        // A^{2^k} = W^{8*2^k}: k=0 -> pow[7] (W^8), k=1 -> pow[8] (W^16), ...
        k_prefix<<<dim3(4,2,NC - s), blk, 0, stream>>>(src, dst, powb + (size_t)(7 + k) * MS, s);
        float* tmp = src; src = dst; dst = tmp;
    }

    k_corr<<<dim3(4,2,TT), blk, 0, stream>>>(src, powb, Xout, Yout);
}

// Round 2
// 902.042 us; speedup vs baseline: 1.4153x; 1.4153x over previous
//
#include <hip/hip_runtime.h>
#include <hip/hip_bf16.h>
#include <cstddef>

#define NXX 512
#define NUU 128
#define NDD 64
#define BB  256
#define TT  256
#define CL  8
#define NC  32
#define BS  (BB * NXX)     // one timestep slab (floats)
#define MS  (NXX * NXX)    // one 512x512 matrix (elements)
#define LDK 32             // LDS row stride in bf16 elems — NO pad; 16B-granular access is balanced

typedef __attribute__((ext_vector_type(8))) short short8;
typedef __attribute__((ext_vector_type(8))) unsigned short ushort8;
typedef __attribute__((ext_vector_type(4))) float f32x4;

__device__ __forceinline__ unsigned short f2bf(float f) {
    union { float f; unsigned u; } v; v.f = f;
    unsigned r = v.u + 0x7FFFu + ((v.u >> 16) & 1u);   // RNE
    return (unsigned short)(r >> 16);
}

enum StageKind { SK_F32_NAT, SK_BF16_NAT, SK_BF16_TRANS };

// Stage a 128x32 operand tile into LDS bf16 [128][LDK].
//  SK_F32_NAT  : src f32 row-major [r][k], rows r0.., cols k0..  (convert + 16B ds_write)
//  SK_BF16_NAT : src bf16 row-major [r][k] -> global_load_lds dwordx4 (zero-VALU DMA)
//  SK_BF16_TRANS: src bf16 [m][n]; S[n - r0][m - k0] = src[m][n]  (k_pow only; conflicts OK)
template<StageKind SK>
__device__ __forceinline__ void stage_tile(const void* src, int ld, int r0, int k0,
                                           unsigned short (*S)[LDK])
{
    const int tid = threadIdx.x;
    if constexpr (SK == SK_F32_NAT) {
        const float* s = (const float*)src;
#pragma unroll
        for (int i = 0; i < 2; ++i) {
            int idx = tid + i * 256;          // 0..511
            int r   = idx >> 2;               // 0..127
            int c   = (idx & 3) << 3;         // 0,8,16,24
            const float* p = s + (size_t)(r0 + r) * ld + k0 + c;
            float4 a = *(const float4*)p;
            float4 b = *(const float4*)(p + 4);
            ushort8 h = { f2bf(a.x), f2bf(a.y), f2bf(a.z), f2bf(a.w),
                          f2bf(b.x), f2bf(b.y), f2bf(b.z), f2bf(b.w) };
            *(ushort8*)&S[r][c] = h;
        }
    } else if constexpr (SK == SK_BF16_NAT) {
        const unsigned short* s = (const unsigned short*)src;
        const int wave = tid >> 6, lane = tid & 63;
#pragma unroll
        for (int i = 0; i < 2; ++i) {
            int rb = wave * 16 + i * 64;      // wave-uniform row base
            int r  = rb + (lane >> 2);
            int c  = (lane & 3) << 3;
            const unsigned short* g = s + (size_t)(r0 + r) * ld + k0 + c;
            // LDS dest = wave-uniform base + lane*16 == &S[rb + lane/4][(lane&3)*8]
            __builtin_amdgcn_global_load_lds(
                (const __attribute__((address_space(1))) void*)g,
                (__attribute__((address_space(3))) void*)&S[rb][0],
                16, 0, 0);
        }
    } else { // SK_BF16_TRANS
        const unsigned short* s = (const unsigned short*)src;
#pragma unroll
        for (int i = 0; i < 2; ++i) {
            int idx = tid + i * 256;
            int m   = idx >> 4;               // 0..31 (contraction)
            int c   = (idx & 15) << 3;        // 0..120 (output col within tile)
            ushort8 v = *(const ushort8*)(s + (size_t)(k0 + m) * ld + r0 + c);
#pragma unroll
            for (int j = 0; j < 8; ++j) S[c + j][m] = v[j];
        }
    }
}

template<StageKind AK, StageKind BK>
__device__ __forceinline__ void gemm_mainloop(
    f32x4 (&acc)[4][4],
    const void* A, int lda, const void* B, int ldb,
    int K, int row0, int n0,
    unsigned short (*As)[LDK], unsigned short (*Bs)[LDK])
{
    const int tid  = threadIdx.x;
    const int lane = tid & 63;
    const int wave = tid >> 6;
    const int wm   = (wave >> 1) * 64;
    const int wn   = (wave & 1) * 64;
    const int l16  = lane & 15;
    const int quad = lane >> 4;

    for (int k0 = 0; k0 < K; k0 += 32) {
        __syncthreads();
        stage_tile<AK>(A, lda, row0, k0, As);
        stage_tile<BK>(B, ldb, n0,   k0, Bs);
        __syncthreads();
        short8 af[4], bfr[4];
#pragma unroll
        for (int f = 0; f < 4; ++f)
            af[f] = *(const short8*)&As[wm + f * 16 + l16][quad * 8];
#pragma unroll
        for (int f = 0; f < 4; ++f)
            bfr[f] = *(const short8*)&Bs[wn + f * 16 + l16][quad * 8];
#pragma unroll
        for (int fm = 0; fm < 4; ++fm)
#pragma unroll
            for (int fn = 0; fn < 4; ++fn)
                acc[fm][fn] = __builtin_amdgcn_mfma_f32_16x16x32_bf16(
                    af[fm], bfr[fn], acc[fm][fn], 0, 0, 0);
    }
}

// D (f32, ld=512) = acc (+Cadd). Yrow: optional Y[m] for global col 511.
__device__ __forceinline__ void gemm_epilogue_f32(
    f32x4 (&acc)[4][4], const float* __restrict__ Cadd,
    float* __restrict__ D, int row0, int n0, float* __restrict__ Yrow)
{
    const int tid  = threadIdx.x;
    const int lane = tid & 63;
    const int wave = tid >> 6;
    const int wm   = (wave >> 1) * 64;
    const int wn   = (wave & 1) * 64;
    const int l16  = lane & 15;
    const int quad = lane >> 4;
#pragma unroll
    for (int fm = 0; fm < 4; ++fm)
#pragma unroll
        for (int fn = 0; fn < 4; ++fn)
#pragma unroll
            for (int r = 0; r < 4; ++r) {
                int m = row0 + wm + fm * 16 + quad * 4 + r;
                int n = n0 + wn + fn * 16 + l16;
                size_t off = (size_t)m * NXX + n;
                float val = acc[fm][fn][r];
                if (Cadd) val += Cadd[off];
                D[off] = val;
                if (Yrow && n == NXX - 1) Yrow[m] = val;
            }
}

// bf16 epilogue for the power chain: T_d stored bf16 [n][k]
__device__ __forceinline__ void gemm_epilogue_bf16(
    f32x4 (&acc)[4][4], unsigned short* __restrict__ D, int row0, int n0)
{
    const int tid  = threadIdx.x;
    const int lane = tid & 63;
    const int wave = tid >> 6;
    const int wm   = (wave >> 1) * 64;
    const int wn   = (wave & 1) * 64;
    const int l16  = lane & 15;
    const int quad = lane >> 4;
#pragma unroll
    for (int fm = 0; fm < 4; ++fm)
#pragma unroll
        for (int fn = 0; fn < 4; ++fn)
#pragma unroll
            for (int r = 0; r < 4; ++r) {
                int m = row0 + wm + fm * 16 + quad * 4 + r;
                int n = n0 + wn + fn * 16 + l16;
                D[(size_t)m * NXX + n] = f2bf(acc[fm][fn][r]);
            }
}

// T1[n][k] = (1 - 0.1*sigmoid(Asc[n][k])) * softmax(Aw[n,:])[k], bf16, row-contiguous.
__global__ __launch_bounds__(256) void k_weff(
    const float* __restrict__ Aw, const float* __restrict__ Asc,
    unsigned short* __restrict__ T1)
{
    const int n   = blockIdx.x;
    const int tid = threadIdx.x;
    const int lane = tid & 63, wave = tid >> 6;
    float v0 = Aw[(size_t)n * NXX + tid];
    float v1 = Aw[(size_t)n * NXX + 256 + tid];
    __shared__ float sred[4];
    float m = fmaxf(v0, v1);
#pragma unroll
    for (int off = 32; off; off >>= 1) m = fmaxf(m, __shfl_down(m, off));
    if (lane == 0) sred[wave] = m;
    __syncthreads();
    if (tid == 0) sred[0] = fmaxf(fmaxf(sred[0], sred[1]), fmaxf(sred[2], sred[3]));
    __syncthreads();
    const float mm = sred[0];
    __syncthreads();
    float e0 = expf(v0 - mm), e1 = expf(v1 - mm);
    float s = e0 + e1;
#pragma unroll
    for (int off = 32; off; off >>= 1) s += __shfl_down(s, off);
    if (lane == 0) sred[wave] = s;
    __syncthreads();
    if (tid == 0) sred[0] = sred[0] + sred[1] + sred[2] + sred[3];
    __syncthreads();
    const float inv = 1.0f / sred[0];
    float sc0 = 1.0f - 0.1f * (1.0f / (1.0f + expf(-Asc[(size_t)n * NXX + tid])));
    float sc1 = 1.0f - 0.1f * (1.0f / (1.0f + expf(-Asc[(size_t)n * NXX + 256 + tid])));
    unsigned short* out = T1 + (size_t)n * NXX;
    out[tid]       = f2bf(sc0 * e0 * inv);
    out[tid + 256] = f2bf(sc1 * e1 * inv);
}

// Power chain products in T-space (exponents add; W-powers commute):
// T_d = gemm(A = T_a natural, B = T_b transpose-staged)
struct PowArgs { int a[4]; int b[4]; int d[4]; };

__global__ __launch_bounds__(256) void k_pow(unsigned short* __restrict__ powb, PowArgs pa)
{
    const int t = blockIdx.z;
    const unsigned short* A = powb + (size_t)pa.a[t] * MS;
    const unsigned short* B = powb + (size_t)pa.b[t] * MS;
    unsigned short*       D = powb + (size_t)pa.d[t] * MS;
    __shared__ unsigned short As[128][LDK];
    __shared__ unsigned short Bs[128][LDK];
    f32x4 acc[4][4] = {};
    const int row0 = blockIdx.y * 128, n0 = blockIdx.x * 128;
    gemm_mainloop<SK_BF16_NAT, SK_BF16_TRANS>(acc, A, NXX, B, NXX, NXX, row0, n0, As, Bs);
    gemm_epilogue_bf16(acc, D, row0, n0);
}

// inj_t = U[t] @ Bw^T + D[t] @ Ew^T  (Bw [NX][NU], Ew [NX][ND] are B-natural already)
__global__ __launch_bounds__(256) void k_inj(
    const float* __restrict__ U, const float* __restrict__ Dm,
    const float* __restrict__ Bw, const float* __restrict__ Ew,
    float* __restrict__ Xp)
{
    const int t = blockIdx.z;
    __shared__ unsigned short As[128][LDK];
    __shared__ unsigned short Bs[128][LDK];
    f32x4 acc[4][4] = {};
    const int row0 = blockIdx.y * 128, n0 = blockIdx.x * 128;
    gemm_mainloop<SK_F32_NAT, SK_F32_NAT>(acc, U  + (size_t)t * BB * NUU, NUU, Bw, NUU, NUU, row0, n0, As, Bs);
    gemm_mainloop<SK_F32_NAT, SK_F32_NAT>(acc, Dm + (size_t)t * BB * NDD, NDD, Ew, NDD, NDD, row0, n0, As, Bs);
    gemm_epilogue_f32(acc, nullptr, Xp + (size_t)t * BS, row0, n0, nullptr);
}

// Within-chunk zero-init scan step j: Xp[c*8+j] += Xp[c*8+j-1] @ W   (W = T1 bf16)
__global__ __launch_bounds__(256) void k_scan(
    float* __restrict__ Xp, const unsigned short* __restrict__ T1, int j)
{
    const int c = blockIdx.z;
    const float* Ap = Xp + (size_t)(c * CL + j - 1) * BS;
    float*       Dp = Xp + (size_t)(c * CL + j) * BS;
    __shared__ unsigned short As[128][LDK];
    __shared__ unsigned short Bs[128][LDK];
    f32x4 acc[4][4] = {};
    const int row0 = blockIdx.y * 128, n0 = blockIdx.x * 128;
    gemm_mainloop<SK_F32_NAT, SK_BF16_NAT>(acc, Ap, NXX, T1, NXX, NXX, row0, n0, As, Bs);
    gemm_epilogue_f32(acc, Dp, Dp, row0, n0, nullptr);
}

__device__ __forceinline__ void copy_tile_f32(const float* __restrict__ src,
                                              float* __restrict__ dst, int row0, int n0)
{
    const int tid = threadIdx.x;
#pragma unroll
    for (int i = 0; i < 16; ++i) {
        int idx = tid + i * 256;          // 4096 float4s = 128x128 f32
        int r   = idx >> 5;
        int cc  = (idx & 31) << 2;
        *(float4*)(dst + (size_t)(row0 + r) * NXX + n0 + cc) =
            *(const float4*)(src + (size_t)(row0 + r) * NXX + n0 + cc);
    }
}

// Prefix step s=1, with v0 read implicitly from (x, Xp):  v1[c] = v0[c] + v0[c-1] @ W^8
__global__ __launch_bounds__(256) void k_prefix_first(
    const float* __restrict__ x, const float* __restrict__ Xp,
    const unsigned short* __restrict__ A8, float* __restrict__ vdst)
{
    const int c = blockIdx.z;
    const int row0 = blockIdx.y * 128, n0 = blockIdx.x * 128;
    if (c == 0) { copy_tile_f32(x, vdst, row0, n0); return; }
    const float* Ap = (c == 1) ? x : Xp + (size_t)((c - 1) * CL - 1) * BS;
    const float* Cp = Xp + (size_t)(c * CL - 1) * BS;
    __shared__ unsigned short As[128][LDK];
    __shared__ unsigned short Bs[128][LDK];
    f32x4 acc[4][4] = {};
    gemm_mainloop<SK_F32_NAT, SK_BF16_NAT>(acc, Ap, NXX, A8, NXX, NXX, row0, n0, As, Bs);
    gemm_epilogue_f32(acc, Cp, vdst + (size_t)c * BS, row0, n0, nullptr);
}

// General Hillis-Steele step: c<s copy; else vdst[c] = vsrc[c] + vsrc[c-s] @ Am
__global__ __launch_bounds__(256) void k_prefix(
    const float* __restrict__ vsrc, float* __restrict__ vdst,
    const unsigned short* __restrict__ Am, int s)
{
    const int c = blockIdx.z;
    const int row0 = blockIdx.y * 128, n0 = blockIdx.x * 128;
    if (c < s) {
        copy_tile_f32(vsrc + (size_t)c * BS, vdst + (size_t)c * BS, row0, n0);
        return;
    }
    const float* Ap = vsrc + (size_t)(c - s) * BS;
    const float* Cp = vsrc + (size_t)c * BS;
    __shared__ unsigned short As[128][LDK];
    __shared__ unsigned short Bs[128][LDK];
    f32x4 acc[4][4] = {};
    gemm_mainloop<SK_F32_NAT, SK_BF16_NAT>(acc, Ap, NXX, Am, NXX, NXX, row0, n0, As, Bs);
    gemm_epilogue_f32(acc, Cp, vdst + (size_t)c * BS, row0, n0, nullptr);
}

// X[c*8+j] = X'[c*8+j] + v[c] @ W^{j+1};  Y[t][b] = X[t][b][511]
__global__ __launch_bounds__(256) void k_corr(
    const float* __restrict__ v, const unsigned short* __restrict__ powb,
    float* __restrict__ X, float* __restrict__ Y)
{
    const int z = blockIdx.z;
    const int c = z >> 3, j = z & 7;
    const float* Ap = v + (size_t)c * BS;
    const unsigned short* Bp = powb + (size_t)j * MS;   // slot j = W^{j+1}
    float* Dp = X + (size_t)z * BS;
    __shared__ unsigned short As[128][LDK];
    __shared__ unsigned short Bs[128][LDK];
    f32x4 acc[4][4] = {};
    const int row0 = blockIdx.y * 128, n0 = blockIdx.x * 128;
    gemm_mainloop<SK_F32_NAT, SK_BF16_NAT>(acc, Ap, NXX, Bp, NXX, NXX, row0, n0, As, Bs);
    gemm_epilogue_f32(acc, Dp, Dp, row0, n0, Y + (size_t)z * BB);
}

extern "C" void kernel_launch(void* const* d_in, const int* in_sizes, int n_in,
                              void* d_out, int out_size, void* d_ws, size_t ws_size,
                              hipStream_t stream)
{
    const float* x   = (const float*)d_in[0];
    const float* U   = (const float*)d_in[1];
    const float* Dm  = (const float*)d_in[2];
    const float* Aw  = (const float*)d_in[3];
    const float* Asc = (const float*)d_in[4];
    const float* Bw  = (const float*)d_in[5];
    const float* Ew  = (const float*)d_in[6];

    float* Xout = (float*)d_out;
    float* Yout = Xout + (size_t)TT * BB * NXX;

    // ws: 12 bf16 transposed powers (6.3 MB) + 2 f32 ping-pong chunk-state buffers (33.6 MB)
    unsigned short* powb = (unsigned short*)d_ws;   // slot s<8: W^{s+1}; slots 8..11: W^{16,32,64,128}
    float* v0 = (float*)(powb + (size_t)12 * MS);
    float* v1 = v0 + (size_t)NC * BS;

    dim3 blk(256);

    k_weff<<<dim3(512), blk, 0, stream>>>(Aw, Asc, powb);

    { PowArgs p{{0},{0},{1}};                   k_pow<<<dim3(4,4,1), blk, 0, stream>>>(powb, p); }
    { PowArgs p{{1,1},{0,1},{2,3}};             k_pow<<<dim3(4,4,2), blk, 0, stream>>>(powb, p); }
    { PowArgs p{{3,3,3,3},{0,1,2,3},{4,5,6,7}}; k_pow<<<dim3(4,4,4), blk, 0, stream>>>(powb, p); }
    { PowArgs p{{7},{7},{8}};                   k_pow<<<dim3(4,4,1), blk, 0, stream>>>(powb, p); }
    { PowArgs p{{8},{8},{9}};                   k_pow<<<dim3(4,4,1), blk, 0, stream>>>(powb, p); }
    { PowArgs p{{9},{9},{10}};                  k_pow<<<dim3(4,4,1), blk, 0, stream>>>(powb, p); }
    { PowArgs p{{10},{10},{11}};                k_pow<<<dim3(4,4,1), blk, 0, stream>>>(powb, p); }

    k_inj<<<dim3(4,2,TT), blk, 0, stream>>>(U, Dm, Bw, Ew, Xout);

    for (int j = 1; j < CL; ++j)
        k_scan<<<dim3(4,2,NC), blk, 0, stream>>>(Xout, powb, j);

    // chunk-start prefix (Hillis-Steele over A = W^8): 5 steps, copy folded in
    k_prefix_first<<<dim3(4,2,NC), blk, 0, stream>>>(x, Xout, powb + (size_t)7 * MS, v1);
    k_prefix<<<dim3(4,2,NC), blk, 0, stream>>>(v1, v0, powb + (size_t)8  * MS, 2);
    k_prefix<<<dim3(4,2,NC), blk, 0, stream>>>(v0, v1, powb + (size_t)9  * MS, 4);
    k_prefix<<<dim3(4,2,NC), blk, 0, stream>>>(v1, v0, powb + (size_t)10 * MS, 8);
    k_prefix<<<dim3(4,2,NC), blk, 0, stream>>>(v0, v1, powb + (size_t)11 * MS, 16);

    k_corr<<<dim3(4,2,TT), blk, 0, stream>>>(v1, powb, Xout, Yout);
}

// Round 3
// 845.864 us; speedup vs baseline: 1.5093x; 1.0664x over previous
//
#include <hip/hip_runtime.h>
#include <hip/hip_bf16.h>
#include <cstddef>

#define NXX 512
#define NUU 128
#define NDD 64
#define BB  256
#define TT  256
#define CL  8
#define NC  32
#define BS  (BB * NXX)     // one slab in elements (256*512)
#define MS  (NXX * NXX)    // one 512x512 matrix in elements
#define LDK 32             // LDS row stride (bf16) for 128x32 staging tiles

typedef __attribute__((ext_vector_type(8))) short short8;
typedef __attribute__((ext_vector_type(8))) unsigned short ushort8;
typedef __attribute__((ext_vector_type(4))) unsigned short ushort4v;
typedef __attribute__((ext_vector_type(4))) float f32x4;

__device__ __forceinline__ unsigned short f2bf(float f) {
    union { float f; unsigned u; } v; v.f = f;
    unsigned r = v.u + 0x7FFFu + ((v.u >> 16) & 1u);   // RNE
    return (unsigned short)(r >> 16);
}
__device__ __forceinline__ float bf2f(unsigned short h) {
    union { unsigned u; float f; } v; v.u = ((unsigned)h) << 16;
    return v.f;
}

// ---------------------------------------------------------------------------
// 128x128-tile GEMM machinery (used by k_pow / k_hs) — proven in round 2.
// ---------------------------------------------------------------------------
enum StageKind { SK_BF16_NAT, SK_BF16_TRANS };

template<StageKind SK>
__device__ __forceinline__ void stage_tile(const void* src, int ld, int r0, int k0,
                                           unsigned short (*S)[LDK])
{
    const int tid = threadIdx.x;
    if constexpr (SK == SK_BF16_NAT) {
        const unsigned short* s = (const unsigned short*)src;
        const int wave = tid >> 6, lane = tid & 63;
#pragma unroll
        for (int i = 0; i < 2; ++i) {
            int rb = wave * 16 + i * 64;      // wave-uniform row base
            int r  = rb + (lane >> 2);
            int c  = (lane & 3) << 3;
            const unsigned short* g = s + (size_t)(r0 + r) * ld + k0 + c;
            __builtin_amdgcn_global_load_lds(
                (const __attribute__((address_space(1))) void*)g,
                (__attribute__((address_space(3))) void*)&S[rb][0],
                16, 0, 0);
        }
    } else { // SK_BF16_TRANS
        const unsigned short* s = (const unsigned short*)src;
#pragma unroll
        for (int i = 0; i < 2; ++i) {
            int idx = tid + i * 256;
            int m   = idx >> 4;               // 0..31 contraction row
            int c   = (idx & 15) << 3;        // 0..120 output col
            ushort8 v = *(const ushort8*)(s + (size_t)(k0 + m) * ld + r0 + c);
#pragma unroll
            for (int j = 0; j < 8; ++j) S[c + j][m] = v[j];
        }
    }
}

template<StageKind AK, StageKind BK>
__device__ __forceinline__ void gemm_mainloop(
    f32x4 (&acc)[4][4],
    const void* A, int lda, const void* B, int ldb,
    int K, int row0, int n0,
    unsigned short (*As)[LDK], unsigned short (*Bs)[LDK])
{
    const int tid  = threadIdx.x;
    const int lane = tid & 63;
    const int wave = tid >> 6;
    const int wm   = (wave >> 1) * 64;
    const int wn   = (wave & 1) * 64;
    const int l16  = lane & 15;
    const int quad = lane >> 4;

    for (int k0 = 0; k0 < K; k0 += 32) {
        __syncthreads();
        stage_tile<AK>(A, lda, row0, k0, As);
        stage_tile<BK>(B, ldb, n0,   k0, Bs);
        __syncthreads();
        short8 af[4], bfr[4];
#pragma unroll
        for (int f = 0; f < 4; ++f)
            af[f] = *(const short8*)&As[wm + f * 16 + l16][quad * 8];
#pragma unroll
        for (int f = 0; f < 4; ++f)
            bfr[f] = *(const short8*)&Bs[wn + f * 16 + l16][quad * 8];
#pragma unroll
        for (int fm = 0; fm < 4; ++fm)
#pragma unroll
            for (int fn = 0; fn < 4; ++fn)
                acc[fm][fn] = __builtin_amdgcn_mfma_f32_16x16x32_bf16(
                    af[fm], bfr[fn], acc[fm][fn], 0, 0, 0);
    }
}

// ---------------------------------------------------------------------------
// T1[n][k] = (1 - 0.1*sigmoid(Asc[n][k])) * softmax(Aw[n,:])[k]  (bf16 T-layout)
// ---------------------------------------------------------------------------
__global__ __launch_bounds__(256) void k_weff(
    const float* __restrict__ Aw, const float* __restrict__ Asc,
    unsigned short* __restrict__ T1)
{
    const int n   = blockIdx.x;
    const int tid = threadIdx.x;
    const int lane = tid & 63, wave = tid >> 6;
    float v0 = Aw[(size_t)n * NXX + tid];
    float v1 = Aw[(size_t)n * NXX + 256 + tid];
    __shared__ float sred[4];
    float m = fmaxf(v0, v1);
#pragma unroll
    for (int off = 32; off; off >>= 1) m = fmaxf(m, __shfl_down(m, off));
    if (lane == 0) sred[wave] = m;
    __syncthreads();
    if (tid == 0) sred[0] = fmaxf(fmaxf(sred[0], sred[1]), fmaxf(sred[2], sred[3]));
    __syncthreads();
    const float mm = sred[0];
    __syncthreads();
    float e0 = expf(v0 - mm), e1 = expf(v1 - mm);
    float s = e0 + e1;
#pragma unroll
    for (int off = 32; off; off >>= 1) s += __shfl_down(s, off);
    if (lane == 0) sred[wave] = s;
    __syncthreads();
    if (tid == 0) sred[0] = sred[0] + sred[1] + sred[2] + sred[3];
    __syncthreads();
    const float inv = 1.0f / sred[0];
    float sc0 = 1.0f - 0.1f * (1.0f / (1.0f + expf(-Asc[(size_t)n * NXX + tid])));
    float sc1 = 1.0f - 0.1f * (1.0f / (1.0f + expf(-Asc[(size_t)n * NXX + 256 + tid])));
    unsigned short* out = T1 + (size_t)n * NXX;
    out[tid]       = f2bf(sc0 * e0 * inv);
    out[tid + 256] = f2bf(sc1 * e1 * inv);
}

// ---------------------------------------------------------------------------
// elementwise f32->bf16 prep: Bw (512x128), Ew (512x64), x (256x512 -> G slab 0)
// ---------------------------------------------------------------------------
__global__ __launch_bounds__(256) void k_prep(
    const float* __restrict__ Bw, const float* __restrict__ Ew,
    const float* __restrict__ x,
    unsigned short* __restrict__ Bwb, unsigned short* __restrict__ Ewb,
    unsigned short* __restrict__ G0)
{
    int i = (blockIdx.x * 256 + threadIdx.x) * 4;
    const float* src; unsigned short* dst; int k;
    if (i < 65536)       { src = Bw; dst = Bwb; k = i; }
    else if (i < 98304)  { src = Ew; dst = Ewb; k = i - 65536; }
    else                 { src = x;  dst = G0;  k = i - 98304; }
    float4 v = *(const float4*)(src + k);
    ushort4v h = { f2bf(v.x), f2bf(v.y), f2bf(v.z), f2bf(v.w) };
    *(ushort4v*)(dst + k) = h;
}

// ---------------------------------------------------------------------------
// Power squaring in T-space: slot d = slot a * slot a  (bf16 in/out)
// ---------------------------------------------------------------------------
__global__ __launch_bounds__(256) void k_pow(unsigned short* __restrict__ powb,
                                             int a, int d)
{
    const unsigned short* A = powb + (size_t)a * MS;
    unsigned short*       D = powb + (size_t)d * MS;
    __shared__ unsigned short As[128][LDK];
    __shared__ unsigned short Bs2[128][LDK];
    f32x4 acc[4][4] = {};
    const int row0 = blockIdx.y * 128, n0 = blockIdx.x * 128;
    gemm_mainloop<SK_BF16_NAT, SK_BF16_TRANS>(acc, A, NXX, A, NXX, NXX, row0, n0, As, Bs2);
    const int tid = threadIdx.x;
    const int lane = tid & 63, wave = tid >> 6;
    const int wm = (wave >> 1) * 64, wn = (wave & 1) * 64;
    const int l16 = lane & 15, quad = lane >> 4;
#pragma unroll
    for (int fm = 0; fm < 4; ++fm)
#pragma unroll
        for (int fn = 0; fn < 4; ++fn)
#pragma unroll
            for (int r = 0; r < 4; ++r) {
                int m = row0 + wm + fm * 16 + quad * 4 + r;
                int n = n0 + wn + fn * 16 + l16;
                D[(size_t)m * NXX + n] = f2bf(acc[fm][fn][r]);
            }
}

// ---------------------------------------------------------------------------
// Hillis-Steele prefix step over 32 bf16 chunk-state slabs:
//   c <  s : vdst[c] = vsrc[c]
//   c >= s : vdst[c] = vsrc[c] + vsrc[c-s] @ W^{8s}
// ---------------------------------------------------------------------------
__global__ __launch_bounds__(256) void k_hs(
    const unsigned short* __restrict__ vsrc, unsigned short* __restrict__ vdst,
    const unsigned short* __restrict__ Am, int s)
{
    const int c = blockIdx.z;
    const int row0 = blockIdx.y * 128, n0 = blockIdx.x * 128;
    const int tid = threadIdx.x;
    if (c < s) {
        const unsigned short* sp = vsrc + (size_t)c * BS;
        unsigned short*       dp = vdst + (size_t)c * BS;
#pragma unroll
        for (int i = 0; i < 8; ++i) {
            int idx = tid + i * 256;
            int r = idx >> 4, cc = (idx & 15) << 3;
            *(ushort8*)(dp + (size_t)(row0 + r) * NXX + n0 + cc) =
                *(const ushort8*)(sp + (size_t)(row0 + r) * NXX + n0 + cc);
        }
        return;
    }
    __shared__ unsigned short As[128][LDK];
    __shared__ unsigned short Bs2[128][LDK];
    f32x4 acc[4][4] = {};
    gemm_mainloop<SK_BF16_NAT, SK_BF16_NAT>(acc, vsrc + (size_t)(c - s) * BS, NXX,
                                            Am, NXX, NXX, row0, n0, As, Bs2);
    const int lane = tid & 63, wave = tid >> 6;
    const int wm = (wave >> 1) * 64, wn = (wave & 1) * 64;
    const int l16 = lane & 15, quad = lane >> 4;
    const unsigned short* Cp = vsrc + (size_t)c * BS;
    unsigned short*       Dp = vdst + (size_t)c * BS;
#pragma unroll
    for (int fm = 0; fm < 4; ++fm)
#pragma unroll
        for (int fn = 0; fn < 4; ++fn)
#pragma unroll
            for (int r = 0; r < 4; ++r) {
                int m = row0 + wm + fm * 16 + quad * 4 + r;
                int n = n0 + wn + fn * 16 + l16;
                float v = acc[fm][fn][r] + bf2f(Cp[(size_t)m * NXX + n]);
                Dp[(size_t)m * NXX + n] = f2bf(v);
            }
}

// ---------------------------------------------------------------------------
// Fused per-chunk recurrence. Block = (chunk c, 32 batch rows). State 32x512
// lives in C-frags; LDS round-trip (bf16) provides next step's A-operand.
// Each step also computes inj_t = U[t]@Bw^T + D[t]@Ew^T in-register (K=192).
//  PHASE_C=false: zero-init; writes chunk-end state to Gout slab c+1 (bf16).
//  PHASE_C=true : init state = Vin[c]; writes final X (f32) and Y each step.
// ---------------------------------------------------------------------------
template<bool PHASE_C>
__global__ __launch_bounds__(256) void k_scan_fused(
    const float* __restrict__ U, const float* __restrict__ Dm,
    const unsigned short* __restrict__ Bwb, const unsigned short* __restrict__ Ewb,
    const unsigned short* __restrict__ Wt,
    const unsigned short* __restrict__ Vin,
    unsigned short* __restrict__ Gout,
    float* __restrict__ X, float* __restrict__ Y)
{
    const int c   = blockIdx.x;          // chunk 0..31
    const int r0  = blockIdx.y * 32;     // batch-row base
    const int tid = threadIdx.x;
    const int lane = tid & 63, wave = tid >> 6;
    const int l16 = lane & 15, quad = lane >> 4;

    __shared__ unsigned short Sb[32][520];   // state bf16 (pad 8 -> +4 bank rot)
    __shared__ unsigned short Ub[32][136];   // U tile bf16
    __shared__ unsigned short Db[32][72];    // D tile bf16

    if constexpr (PHASE_C) {
        const unsigned short* vsl = Vin + ((size_t)c * BB + r0) * NXX;
        int row = tid >> 3, col0 = (tid & 7) * 64;
#pragma unroll
        for (int i = 0; i < 8; ++i)
            *(ushort8*)&Sb[row][col0 + i * 8] =
                *(const ushort8*)(vsl + (size_t)row * NXX + col0 + i * 8);
    }

    // per-lane 32-bit element offsets for the 8 n-frags of this wave
    int woff[8], bwoff[8], ewoff[8];
#pragma unroll
    for (int g = 0; g < 8; ++g) {
        int n = wave * 128 + g * 16 + l16;
        woff[g]  = n * NXX + quad * 8;
        bwoff[g] = n * NUU + quad * 8;
        ewoff[g] = n * NDD + quad * 8;
    }

    f32x4 acc[2][8];

    for (int j = 0; j < CL; ++j) {
        const int t = c * CL + j;
        // ---- stage U (32x128) and D (32x64) f32 -> bf16 into LDS ----
        {
            int row = tid >> 3;
            int uc  = (tid & 7) * 16;
            const float* up = U + ((size_t)t * BB + r0 + row) * NUU + uc;
            float4 a0 = *(const float4*)(up);
            float4 a1 = *(const float4*)(up + 4);
            float4 a2 = *(const float4*)(up + 8);
            float4 a3 = *(const float4*)(up + 12);
            ushort8 h0 = { f2bf(a0.x), f2bf(a0.y), f2bf(a0.z), f2bf(a0.w),
                           f2bf(a1.x), f2bf(a1.y), f2bf(a1.z), f2bf(a1.w) };
            ushort8 h1 = { f2bf(a2.x), f2bf(a2.y), f2bf(a2.z), f2bf(a2.w),
                           f2bf(a3.x), f2bf(a3.y), f2bf(a3.z), f2bf(a3.w) };
            int dc = (tid & 7) * 8;
            const float* dp = Dm + ((size_t)t * BB + r0 + row) * NDD + dc;
            float4 b0 = *(const float4*)(dp);
            float4 b1 = *(const float4*)(dp + 4);
            ushort8 hd = { f2bf(b0.x), f2bf(b0.y), f2bf(b0.z), f2bf(b0.w),
                           f2bf(b1.x), f2bf(b1.y), f2bf(b1.z), f2bf(b1.w) };
            *(ushort8*)&Ub[row][uc]     = h0;
            *(ushort8*)&Ub[row][uc + 8] = h1;
            *(ushort8*)&Db[row][dc]     = hd;
        }
        __syncthreads();   // staging (and prev-step Sb writes) visible

#pragma unroll
        for (int f = 0; f < 2; ++f)
#pragma unroll
            for (int g = 0; g < 8; ++g) acc[f][g] = (f32x4){0.f, 0.f, 0.f, 0.f};

        // ---- inj: U @ Bw^T  (K=128) ----
#pragma unroll
        for (int kk = 0; kk < 4; ++kk) {
            short8 a0 = *(const short8*)&Ub[l16][kk * 32 + quad * 8];
            short8 a1 = *(const short8*)&Ub[16 + l16][kk * 32 + quad * 8];
#pragma unroll
            for (int g = 0; g < 8; ++g) {
                short8 b = *(const short8*)(Bwb + bwoff[g] + kk * 32);
                acc[0][g] = __builtin_amdgcn_mfma_f32_16x16x32_bf16(a0, b, acc[0][g], 0, 0, 0);
                acc[1][g] = __builtin_amdgcn_mfma_f32_16x16x32_bf16(a1, b, acc[1][g], 0, 0, 0);
            }
        }
        // ---- inj: D @ Ew^T  (K=64) ----
#pragma unroll
        for (int kk = 0; kk < 2; ++kk) {
            short8 a0 = *(const short8*)&Db[l16][kk * 32 + quad * 8];
            short8 a1 = *(const short8*)&Db[16 + l16][kk * 32 + quad * 8];
#pragma unroll
            for (int g = 0; g < 8; ++g) {
                short8 b = *(const short8*)(Ewb + ewoff[g] + kk * 32);
                acc[0][g] = __builtin_amdgcn_mfma_f32_16x16x32_bf16(a0, b, acc[0][g], 0, 0, 0);
                acc[1][g] = __builtin_amdgcn_mfma_f32_16x16x32_bf16(a1, b, acc[1][g], 0, 0, 0);
            }
        }
        // ---- state @ W  (K=512) ----
        if (PHASE_C || j > 0) {
#pragma unroll
            for (int kk = 0; kk < 16; ++kk) {
                short8 a0 = *(const short8*)&Sb[l16][kk * 32 + quad * 8];
                short8 a1 = *(const short8*)&Sb[16 + l16][kk * 32 + quad * 8];
#pragma unroll
                for (int g = 0; g < 8; ++g) {
                    short8 b = *(const short8*)(Wt + woff[g] + kk * 32);
                    acc[0][g] = __builtin_amdgcn_mfma_f32_16x16x32_bf16(a0, b, acc[0][g], 0, 0, 0);
                    acc[1][g] = __builtin_amdgcn_mfma_f32_16x16x32_bf16(a1, b, acc[1][g], 0, 0, 0);
                }
            }
        }
        __syncthreads();   // all reads of Sb done before overwrite

        // ---- write new state (and outputs) ----
#pragma unroll
        for (int f = 0; f < 2; ++f)
#pragma unroll
            for (int g = 0; g < 8; ++g) {
                int n = wave * 128 + g * 16 + l16;
#pragma unroll
                for (int rr = 0; rr < 4; ++rr) {
                    int mr = f * 16 + quad * 4 + rr;
                    float v = acc[f][g][rr];
                    unsigned short hb = f2bf(v);
                    Sb[mr][n] = hb;
                    if constexpr (PHASE_C) {
                        X[((size_t)t * BB + r0 + mr) * NXX + n] = v;
                        if (n == NXX - 1) Y[(size_t)t * BB + r0 + mr] = v;
                    } else {
                        if (j == CL - 1)
                            Gout[((size_t)(c + 1) * BB + r0 + mr) * NXX + n] = hb;
                    }
                }
            }
    }
}

// ---------------------------------------------------------------------------
extern "C" void kernel_launch(void* const* d_in, const int* in_sizes, int n_in,
                              void* d_out, int out_size, void* d_ws, size_t ws_size,
                              hipStream_t stream)
{
    const float* x   = (const float*)d_in[0];
    const float* U   = (const float*)d_in[1];
    const float* Dm  = (const float*)d_in[2];
    const float* Aw  = (const float*)d_in[3];
    const float* Asc = (const float*)d_in[4];
    const float* Bw  = (const float*)d_in[5];
    const float* Ew  = (const float*)d_in[6];

    float* Xout = (float*)d_out;
    float* Yout = Xout + (size_t)TT * BB * NXX;

    // ws layout (bf16): powers slots 0..7 = W^{1,2,4,8,16,32,64,128};
    // Bwb 512x128; Ewb 512x64; G 33 slabs; vA 32; vB 32  (~30 MB total)
    unsigned short* powb = (unsigned short*)d_ws;
    unsigned short* Bwb  = powb + (size_t)8 * MS;
    unsigned short* Ewb  = Bwb + (size_t)NXX * NUU;
    unsigned short* Gbuf = Ewb + (size_t)NXX * NDD;
    unsigned short* vA   = Gbuf + (size_t)(NC + 1) * BS;
    unsigned short* vB   = vA + (size_t)NC * BS;

    dim3 blk(256);

    k_weff<<<dim3(512), blk, 0, stream>>>(Aw, Asc, powb);
    k_prep<<<dim3(224), blk, 0, stream>>>(Bw, Ew, x, Bwb, Ewb, Gbuf);

    // squaring chain: slot i -> slot i+1  (W^1 -> W^2 -> ... -> W^128)
    for (int i = 0; i < 7; ++i)
        k_pow<<<dim3(4, 4), blk, 0, stream>>>(powb, i, i + 1);

    // Pass A: zero-init chunk scans -> chunk-end states into G[1..32]
    k_scan_fused<false><<<dim3(NC, 8), blk, 0, stream>>>(
        U, Dm, Bwb, Ewb, powb, nullptr, Gbuf, nullptr, nullptr);

    // Hillis-Steele prefix over chunk-start states (bf16 slabs)
    k_hs<<<dim3(4, 2, NC), blk, 0, stream>>>(Gbuf, vA, powb + (size_t)3 * MS, 1);
    k_hs<<<dim3(4, 2, NC), blk, 0, stream>>>(vA, vB, powb + (size_t)4 * MS, 2);
    k_hs<<<dim3(4, 2, NC), blk, 0, stream>>>(vB, vA, powb + (size_t)5 * MS, 4);
    k_hs<<<dim3(4, 2, NC), blk, 0, stream>>>(vA, vB, powb + (size_t)6 * MS, 8);
    k_hs<<<dim3(4, 2, NC), blk, 0, stream>>>(vB, vA, powb + (size_t)7 * MS, 16);

    // Pass C: seeded chunk scans -> final X (f32) and Y
    k_scan_fused<true><<<dim3(NC, 8), blk, 0, stream>>>(
        U, Dm, Bwb, Ewb, powb, vA, nullptr, Xout, Yout);
}